// Round 15
// baseline (133.315 us; speedup 1.0000x reference)
//
#include <hip/hip_runtime.h>
#include <math.h>

// B,S,D,V,N_BLOCKS = 4096,128,9,5,4
constexpr int Bn = 4096;
constexpr int Sn = 128;
constexpr int Dn = 9;
constexpr int Vn = 5;
constexpr int NBn = 4;

typedef float f4 __attribute__((ext_vector_type(4)));
typedef _Float16 h8 __attribute__((ext_vector_type(8)));   // MFMA operand type
typedef __fp16   h2 __attribute__((ext_vector_type(2)));
typedef unsigned u4v __attribute__((ext_vector_type(4)));
typedef short s4v __attribute__((ext_vector_type(4)));

// Workspace layout:
//  floats [it*96 + e*9 + d] = M'[e][d] = qs * sum_f Wk[f][e]*Wq[f][d]
//  floats [it*96 + 81 + d]  = w'[d]   = qs * sum_f Wk[f][d]*bq[f]
//  floats [384 .. 1536)     = PE[r][d] positional encoding
//  bytes  [6144 .. 14336)   = fp16 MFMA A-fragment table (prep2):
//     [it][op][e][s] halves, idx = it*1024 + op*512 + e*32 + s
//     op0 (Y-proj): rows e<9 = [Mh(9)|Mh(9)|Ml(9)|0^5]; e=9 = [wh|wh|wl|0^5]
//     op1 (V-proj): rows e<9 = [Wvh|Wvh|Wvl|0|0|0|bvh,bvl]; else 0
// Softmax shift invariance: S[q][k] = x_q M x_k + w'.x_k (+ per-q consts that
// cancel), so K-side needs NO projection and bk drops out entirely.
constexpr int WS_PE = 384;
constexpr int WS_FRAG_BYTES = 6144;

// R8 POST-MORTEM: MFMA-izing projections cut VALU issue 35->29us but wall
// stayed 62.6us — the 4 barriers/layer convert saved cycles into convoy
// stall (~54% of wall). R9: BARRIER-BRACKETED READS. All staging is
// wave-local (each wave stages its OWN 32 rows: KF/QF/VF writes, Y/V MFMAs,
// XB round-trips — same-wave lgkmcnt ordering, no barriers). Only the
// attention read set (KF all rows, VF all, QF own) is cross-wave, so the
// layer needs exactly 2 barriers bracketing ~18 LDS reads:
//   bar1(staging done) -> kfr/vf/bq reads -> bar2(reads in regs) ->
//   exp/PV/O-write + NEXT layer staging (wave-local, waves drift freely)
// All heavy compute now sits outside any barrier region.
//
// LDS layout (stride 80B rows = 20 banks, odd multiple of 4):
//  KF [128]x32 fp16 [Xh(9)|Xl(9)|Xh(9)|0,th,tl,1,1], stride 40 shorts
//  QF [128]x32 fp16 [Yh(9)|Yh(9)|Yl(9)|0,1,1,0,0]
//    QK pairing: XhYh + XlYh + XhYl + th + tl  (exact to ~2^-22)
//  VF [16][136] fp16 V^T; row 9 = 1.0 (ones for softmax denom; V-MFMA only
//    writes e<9). Rows 10..15 unwritten.
//  XB [128][12] f32: holds x, then Y (+t at col 9) mid-layer, then O.
// No-max softmax: scores bounded |s|<~12 in log2 domain; exp2 direct is safe
// (fp16 max 2^15.99) and rcp-normalization restores the exact softmax.
constexpr int KF_OFF = 0;          // 10240
constexpr int QF_OFF = 10240;      // 10240
constexpr int VF_OFF = 20480;      // 16*272 = 4352
constexpr int XB_OFF = 24832;      // 6144
constexpr int SMEM_BYTES = 30976;

static __device__ __forceinline__ unsigned pk(_Float16 a, _Float16 b) {
    h2 t; t.x = (__fp16)a; t.y = (__fp16)b;
    return __builtin_bit_cast(unsigned, t);
}

static __device__ __forceinline__ h8 read_quad(const short* base, int row, int quad) {
    return *(const h8*)(base + row * 40 + quad * 8);
}

// prep1: M'/w' folds + PE table (input-only, shared by all blocks).
__global__ void prep_kernel(const float* __restrict__ Wq, const float* __restrict__ bq,
                            const float* __restrict__ Wk, float* __restrict__ ws)
{
    const float qs = (1.0f / 3.0f) * 1.44269504f;   // 1/sqrt(D) * log2(e)
    const int idx = blockIdx.x * 256 + threadIdx.x;
    if (idx < 360) {
        const int it = idx / 90, j = idx % 90;
        const float* wq = Wq + it * 81;
        const float* wk = Wk + it * 81;
        float acc = 0.0f;
        if (j < 81) {
            const int e = j / 9, d = j % 9;
            #pragma unroll
            for (int f = 0; f < 9; ++f) acc = fmaf(wk[f * 9 + e], wq[f * 9 + d], acc);
        } else {
            const int d = j - 81;
            const float* bqp = bq + it * 9;
            #pragma unroll
            for (int f = 0; f < 9; ++f) acc = fmaf(wk[f * 9 + d], bqp[f], acc);
        }
        ws[it * 96 + j] = acc * qs;
    } else if (idx < 360 + Sn * Dn) {
        const int j = idx - 360;
        const int r = j / 9, d = j % 9;
        const float inv_freq[Dn] = {
            1.0f, 1.0f, 0.1291549665f, 0.1291549665f, 0.0166810054f,
            0.0166810054f, 0.0021544347f, 0.0021544347f, 0.0002782559f };
        const float a = (float)r * inv_freq[d];
        ws[WS_PE + j] = (d & 1) ? cosf(a) : sinf(a);
    }
}

// prep2: fp16 A-fragment table for the Y/V projection MFMAs (reads M'/w'
// from ws — separate launch after prep1 guarantees ordering).
__global__ void prep2_kernel(const float* __restrict__ Wv, const float* __restrict__ bv,
                             float* __restrict__ ws)
{
    const int idx = blockIdx.x * 256 + threadIdx.x;
    if (idx >= 4096) return;
    const int it = idx >> 10, rem = idx & 1023, op = rem >> 9;
    const int e = (rem >> 5) & 15, s = rem & 31;
    float v = 0.0f;
    bool lo = false;
    if (s < 27) {
        const int d = (s < 9) ? s : (s < 18 ? s - 9 : s - 18);
        lo = (s >= 18);
        if (op == 0) {
            if (e < 9)       v = ws[it * 96 + e * 9 + d];
            else if (e == 9) v = ws[it * 96 + 81 + d];
        } else {
            if (e < 9)       v = Wv[it * 81 + e * 9 + d];
        }
    } else if (op == 1 && e < 9 && s >= 30) {
        v = bv[it * 9 + e];          // bias hi/lo at slots 30/31 (pairs with 1,1 in KF)
        lo = (s == 31);
    }
    const _Float16 h = (_Float16)v;
    const _Float16 r = lo ? (_Float16)(v - (float)h) : h;
    ((_Float16*)((char*)ws + WS_FRAG_BYTES))[idx] = r;
}

// One block = one batch, 4 waves. Wave wv owns rows [32wv, 32wv+32) for
// staging AND q-tiles {2wv, 2wv+1} for attention (same rows -> all staging
// and O/X round-trips are wave-local).
__global__ __launch_bounds__(256, 4) void bert_kernel(
    const int*   __restrict__ tokens,
    const float* __restrict__ emb,
    const float* __restrict__ Wout, const float* __restrict__ bout,
    const float* __restrict__ wsp,
    float*       __restrict__ out)
{
    __shared__ __align__(16) char smem[SMEM_BYTES];
    short* KF = (short*)(smem + KF_OFF);
    short* QF = (short*)(smem + QF_OFF);
    short* VF = (short*)(smem + VF_OFF);
    float* XB = (float*)(smem + XB_OFF);

    const int b   = blockIdx.x;
    const int tid = threadIdx.x;         // 0..255
    const int t   = tid & 63;
    const int wv  = tid >> 6;            // wave 0..3
    const int col = t & 15;
    const int g   = t >> 4;
    const bool hi = tid >= 128;
    const int r = tid & 127;             // stage-0 / logits row
    const float* PE = wsp + WS_PE;       // [128][9]
    const _Float16* FB = (const _Float16*)((const char*)wsp + WS_FRAG_BYTES);
    const _Float16 one = (_Float16)1.0f;
    const _Float16 z0  = (_Float16)0.0f;

    // wave-local staging row assignment: 2 lanes per row over own 32 rows
    const int srow = wv * 32 + (t >> 1);
    const bool shi = (t & 1) != 0;

    // ---- stage 0: embed + positional encoding -> XB; VF ones row ----
    if (!hi) {
        const int tok = tokens[b * Sn + r];
        float xr[9];
        #pragma unroll
        for (int d = 0; d < Dn; ++d)
            xr[d] = emb[tok * Dn + d] + PE[r * 9 + d];
        f4* xp = (f4*)&XB[r * 12];
        xp[0] = (f4){xr[0], xr[1], xr[2], xr[3]};
        xp[1] = (f4){xr[4], xr[5], xr[6], xr[7]};
        xp[2] = (f4){xr[8], 0.0f, 0.0f, 0.0f};
    } else {
        VF[9 * 136 + r] = (short)0x3C00;   // fp16 1.0 — persists across layers
    }
    __syncthreads();

    // Wave-local staging of layer `it`: (a) KF rows, (b) Y/V MFMAs,
    // (c) QF rows + t-word. All accesses touch only this wave's 32 rows;
    // ordering is same-wave lgkmcnt (no barriers).
    auto stage = [&](int it) {
        const _Float16* fb = FB + it * 1024;
        const h8 aM = *(const h8*)(fb + col * 32 + g * 8);
        const h8 aV = *(const h8*)(fb + 512 + col * 32 + g * 8);

        // (a) KF row srow, half shi
        {
            const f4* xp = (const f4*)&XB[srow * 12];
            f4 a0 = xp[0], a1 = xp[1], a2 = xp[2];
            float x[9] = {a0.x, a0.y, a0.z, a0.w, a1.x, a1.y, a1.z, a1.w, a2.x};
            _Float16 H[9];
            #pragma unroll
            for (int d = 0; d < Dn; ++d) H[d] = (_Float16)x[d];
            u4v* qp = (u4v*)(KF + srow * 40);
            if (!shi) {
                const _Float16 l7 = (_Float16)(x[7] - (float)H[7]);
                const _Float16 l8 = (_Float16)(x[8] - (float)H[8]);
                qp[0] = (u4v){ pk(H[0],H[1]), pk(H[2],H[3]), pk(H[4],H[5]), pk(H[6],H[7]) };
                qp[2] = (u4v){ pk(l7,l8),     pk(H[0],H[1]), pk(H[2],H[3]), pk(H[4],H[5]) };
            } else {
                _Float16 l[7];
                #pragma unroll
                for (int d = 0; d < 7; ++d) l[d] = (_Float16)(x[d] - (float)H[d]);
                qp[1] = (u4v){ pk(H[8],l[0]), pk(l[1],l[2]), pk(l[3],l[4]), pk(l[5],l[6]) };
                // slots 24-31: Xh6,Xh7,Xh8, 0, th,tl (placeholder 0), 1,1
                qp[3] = (u4v){ pk(H[6],H[7]), pk(H[8],z0), 0u, pk(one,one) };
            }
        }

        // (b) Y = M''.x, V = Wv''.x via MFMA over own 2 tiles (B = own KF rows)
        #pragma unroll
        for (int sub = 0; sub < 2; ++sub) {
            const int xrow = (2 * wv + sub) * 16 + col;
            h8 bx = read_quad(KF, xrow, g);
            f4 yD = __builtin_amdgcn_mfma_f32_16x16x32_f16(aM, bx, (f4)(0.0f), 0, 0, 0);
            f4 vD = __builtin_amdgcn_mfma_f32_16x16x32_f16(aV, bx, (f4)(0.0f), 0, 0, 0);
            // D: col=lane&15 -> x-row, row=4g+rr -> e. Y rows 0..8 + t at e=9.
            if (g < 3) *(f4*)&XB[xrow * 12 + g * 4] = yD;
            #pragma unroll
            for (int rr = 0; rr < 4; ++rr) {
                const int e = 4 * g + rr;
                if (e < 9)
                    VF[e * 136 + xrow] = __builtin_bit_cast(short, (_Float16)vD[rr]);
            }
        }

        // (c) QF row srow from Y (XB round-trip, own rows); t-word -> KF
        {
            const f4* xp = (const f4*)&XB[srow * 12];
            f4 b0 = xp[0], b1 = xp[1], b2 = xp[2];
            float y[9] = {b0.x, b0.y, b0.z, b0.w, b1.x, b1.y, b1.z, b1.w, b2.x};
            const float tb = b2.y;          // t at XB col 9
            _Float16 H[9];
            #pragma unroll
            for (int e = 0; e < Dn; ++e) H[e] = (_Float16)y[e];
            u4v* qq = (u4v*)(QF + srow * 40);
            if (!shi) {
                _Float16 l[6];
                #pragma unroll
                for (int e = 0; e < 6; ++e) l[e] = (_Float16)(y[e] - (float)H[e]);
                qq[0] = (u4v){ pk(H[0],H[1]), pk(H[2],H[3]), pk(H[4],H[5]), pk(H[6],H[7]) };
                qq[2] = (u4v){ pk(H[7],H[8]), pk(l[0],l[1]), pk(l[2],l[3]), pk(l[4],l[5]) };
            } else {
                const _Float16 l6 = (_Float16)(y[6] - (float)H[6]);
                const _Float16 l7 = (_Float16)(y[7] - (float)H[7]);
                const _Float16 l8 = (_Float16)(y[8] - (float)H[8]);
                qq[1] = (u4v){ pk(H[8],H[0]), pk(H[1],H[2]), pk(H[3],H[4]), pk(H[5],H[6]) };
                qq[3] = (u4v){ pk(l6,l7),     pk(l8,z0),     pk(one,one),   0u };
                const _Float16 th = (_Float16)tb;
                const _Float16 tl = (_Float16)(tb - (float)th);
                ((unsigned*)(KF + srow * 40))[14] = pk(th, tl);   // slots 28,29
            }
        }
    };

    stage(0);

    #pragma unroll 1
    for (int it = 0; it < NBn; ++it) {
        __syncthreads();                 // bar1: all waves' staging complete

        // ---- attention READ phase (the only cross-wave touches) ----
        h8 kfr[8];
        #pragma unroll
        for (int kt = 0; kt < 8; ++kt)
            kfr[kt] = read_quad(KF, kt * 16 + col, g);

        // V^T A-frags with permuted K-dim: slot (g,j) <-> key 16*(2s+(j>>2))+4g+(j&3)
        h8 vf[4];
        #pragma unroll
        for (int s = 0; s < 4; ++s) {
            const short* p0 = VF + col * 136 + 32 * s + 4 * g;
            s4v va = *(const s4v*)p0;
            s4v vb = *(const s4v*)(p0 + 16);
            vf[s] = __builtin_bit_cast(h8,
                __builtin_shufflevector(va, vb, 0, 1, 2, 3, 4, 5, 6, 7));
        }
        h8 bq0 = read_quad(QF, (2 * wv)     * 16 + col, g);
        h8 bq1 = read_quad(QF, (2 * wv + 1) * 16 + col, g);

        __syncthreads();                 // bar2: all reads in registers

        // ---- attention COMPUTE (wave-local from here on) ----
        #pragma unroll
        for (int ti = 0; ti < 2; ++ti) {
            const int q = (2 * wv + ti) * 16 + col;
            const h8 bq3 = ti ? bq1 : bq0;

            f4 acc[8];
            #pragma unroll
            for (int kt = 0; kt < 8; ++kt)
                acc[kt] = __builtin_amdgcn_mfma_f32_16x16x32_f16(kfr[kt], bq3, (f4)(0.0f), 0, 0, 0);

            // lane holds S^T[key = kt*16 + 4g + rr][q] (log2 domain); exp2 direct.
            #pragma unroll
            for (int kt = 0; kt < 8; ++kt)
                #pragma unroll
                for (int rr = 0; rr < 4; ++rr)
                    acc[kt][rr] = __builtin_amdgcn_exp2f(acc[kt][rr]);

            // P B-frags: slot j=0..3 -> (kt=2s, rr=j); j=4..7 -> (kt=2s+1, rr=j&3)
            f4 oac = (f4)(0.0f);
            #pragma unroll
            for (int s = 0; s < 4; ++s) {
                u4v up = (u4v){
                    __builtin_bit_cast(unsigned, __builtin_amdgcn_cvt_pkrtz(acc[2*s][0],   acc[2*s][1])),
                    __builtin_bit_cast(unsigned, __builtin_amdgcn_cvt_pkrtz(acc[2*s][2],   acc[2*s][3])),
                    __builtin_bit_cast(unsigned, __builtin_amdgcn_cvt_pkrtz(acc[2*s+1][0], acc[2*s+1][1])),
                    __builtin_bit_cast(unsigned, __builtin_amdgcn_cvt_pkrtz(acc[2*s+1][2], acc[2*s+1][3])) };
                oac = __builtin_amdgcn_mfma_f32_16x16x32_f16(vf[s], __builtin_bit_cast(h8, up), oac, 0, 0, 0);
            }
            // denominator: O^T row 9 = sum_k P[k][q], held by lane 32+q, reg 1
            const float sm = __shfl(oac[1], 32 + col);
            const float rl = __builtin_amdgcn_rcpf(sm);
            oac *= rl;
            // O^T C-layout: lane col = q, rows d = 4g + rr; keep d < 12
            if (g < 3)
                *(f4*)&XB[q * 12 + g * 4] = oac;
        }

        // next layer's wave-local staging overlaps other waves' compute
        if (it + 1 < NBn) stage(it + 1);
    }
    __syncthreads();

    // ---- logits + log_softmax ----
    if (!hi) {
        const f4* xp = (const f4*)&XB[r * 12];
        f4 a0 = xp[0], a1 = xp[1], a2 = xp[2];
        float xr[9] = {a0.x, a0.y, a0.z, a0.w, a1.x, a1.y, a1.z, a1.w, a2.x};
        float lg[Vn];
        #pragma unroll
        for (int v = 0; v < Vn; ++v) {
            float a = bout[v];
            #pragma unroll
            for (int d = 0; d < Dn; ++d) a = fmaf(xr[d], Wout[v * Dn + d], a);
            lg[v] = a;
        }
        float mm = lg[0];
        #pragma unroll
        for (int v = 1; v < Vn; ++v) mm = fmaxf(mm, lg[v]);
        float sum = 0.0f;
        #pragma unroll
        for (int v = 0; v < Vn; ++v)
            sum += __builtin_amdgcn_exp2f((lg[v] - mm) * 1.44269504f);
        const float lse = __builtin_amdgcn_logf(sum) * 0.69314718f + mm;
        float* op = out + ((size_t)b * Sn + r) * Vn;
        #pragma unroll
        for (int v = 0; v < Vn; ++v) op[v] = lg[v] - lse;
    }
}

extern "C" void kernel_launch(void* const* d_in, const int* in_sizes, int n_in,
                              void* d_out, int out_size, void* d_ws, size_t ws_size,
                              hipStream_t stream) {
    const int*   tokens = (const int*)  d_in[0];
    const float* emb    = (const float*)d_in[1];
    const float* Wq     = (const float*)d_in[2];
    const float* bq_    = (const float*)d_in[3];
    const float* Wk     = (const float*)d_in[4];
    const float* Wv     = (const float*)d_in[6];
    const float* bv_    = (const float*)d_in[7];
    const float* Wout   = (const float*)d_in[8];
    const float* bout_  = (const float*)d_in[9];
    float* out = (float*)d_out;
    float* ws  = (float*)d_ws;

    prep_kernel<<<dim3(6), dim3(256), 0, stream>>>(Wq, bq_, Wk, ws);
    prep2_kernel<<<dim3(16), dim3(256), 0, stream>>>(Wv, bv_, ws);
    bert_kernel<<<dim3(Bn), dim3(256), 0, stream>>>(
        tokens, emb, Wout, bout_, ws, out);
}